// Round 1
// baseline (381.486 us; speedup 1.0000x reference)
//
#include <hip/hip_runtime.h>
#include <math.h>

#define N_NODES 65536
#define B_GRAPHS 64
#define NPG 1024
#define EPG 16384
#define E_TOTAL (B_GRAPHS * EPG)
#define NEG 0.2f

// ---------------- CSR build ----------------
__global__ void k_deg(const int* __restrict__ dst, int* __restrict__ cnt) {
    int i = blockIdx.x * 256 + threadIdx.x;
    if (i < E_TOTAL) atomicAdd(&cnt[dst[i]], 1);
}

// one block per graph: exclusive scan of 1024 degrees, base = b*EPG
__global__ __launch_bounds__(256) void k_scan(int* __restrict__ cursor, int* __restrict__ rowptr) {
    int b = blockIdx.x, tid = threadIdx.x;
    __shared__ int ps[256];
    int idx = b * NPG + tid * 4;
    int v0 = cursor[idx], v1 = cursor[idx + 1], v2 = cursor[idx + 2], v3 = cursor[idx + 3];
    ps[tid] = v0 + v1 + v2 + v3;
    __syncthreads();
    for (int off = 1; off < 256; off <<= 1) {
        int u = (tid >= off) ? ps[tid - off] : 0;
        __syncthreads();
        ps[tid] += u;
        __syncthreads();
    }
    int ex = (tid ? ps[tid - 1] : 0) + b * EPG;
    int r0 = ex, r1 = r0 + v0, r2 = r1 + v1, r3 = r2 + v2;
    rowptr[idx] = r0; rowptr[idx + 1] = r1; rowptr[idx + 2] = r2; rowptr[idx + 3] = r3;
    cursor[idx] = r0; cursor[idx + 1] = r1; cursor[idx + 2] = r2; cursor[idx + 3] = r3;
    if (b == 0 && tid == 0) rowptr[N_NODES] = E_TOTAL;
}

__global__ void k_scatter(const int* __restrict__ src, const int* __restrict__ dst,
                          int* __restrict__ cursor, int* __restrict__ col) {
    int i = blockIdx.x * 256 + threadIdx.x;
    if (i < E_TOTAL) {
        int d = dst[i];
        int p = atomicAdd(&cursor[d], 1);
        col[p] = src[i];
    }
}

// ---------------- node GEMM: out[n][c] = sum_k X[n][k]*W[k][c] + b[c], c in [0,128) ----------------
template <int K>
__global__ __launch_bounds__(256) void k_gemm(const float* __restrict__ X, const float* __restrict__ W,
                                              const float* __restrict__ bias, float* __restrict__ out) {
    __shared__ float xs[64 * 32];    // 64 nodes x 32 k
    __shared__ float wsh[32 * 128];  // 32 k x 128 c
    int tid = threadIdx.x;
    int ct = tid & 31;   // 32 col-tiles of 4
    int nt = tid >> 5;   // 8 node-tiles of 8
    int nb = blockIdx.x * 64;
    float4 acc[8];
#pragma unroll
    for (int i = 0; i < 8; ++i) acc[i] = make_float4(0.f, 0.f, 0.f, 0.f);

    for (int k0 = 0; k0 < K; k0 += 32) {
        // stage X tile (64 rows x 32 k)
        for (int j = tid; j < 512; j += 256) {
            int r = j >> 3, c4 = j & 7;
            float4 xv = *(const float4*)(X + (size_t)(nb + r) * K + k0 + c4 * 4);
            *(float4*)(xs + r * 32 + c4 * 4) = xv;
        }
        // stage W tile (32 rows x 128 c) — contiguous chunk
        for (int j = tid; j < 1024; j += 256) {
            float4 wv = *(const float4*)(W + (size_t)k0 * 128 + j * 4);
            *(float4*)(wsh + j * 4) = wv;
        }
        __syncthreads();
#pragma unroll
        for (int k4 = 0; k4 < 8; ++k4) {
            float4 wv0 = *(const float4*)(wsh + (k4 * 4 + 0) * 128 + ct * 4);
            float4 wv1 = *(const float4*)(wsh + (k4 * 4 + 1) * 128 + ct * 4);
            float4 wv2 = *(const float4*)(wsh + (k4 * 4 + 2) * 128 + ct * 4);
            float4 wv3 = *(const float4*)(wsh + (k4 * 4 + 3) * 128 + ct * 4);
#pragma unroll
            for (int i = 0; i < 8; ++i) {
                float4 xv = *(const float4*)(xs + (nt * 8 + i) * 32 + k4 * 4);
                acc[i].x = fmaf(xv.x, wv0.x, acc[i].x); acc[i].x = fmaf(xv.y, wv1.x, acc[i].x);
                acc[i].x = fmaf(xv.z, wv2.x, acc[i].x); acc[i].x = fmaf(xv.w, wv3.x, acc[i].x);
                acc[i].y = fmaf(xv.x, wv0.y, acc[i].y); acc[i].y = fmaf(xv.y, wv1.y, acc[i].y);
                acc[i].y = fmaf(xv.z, wv2.y, acc[i].y); acc[i].y = fmaf(xv.w, wv3.y, acc[i].y);
                acc[i].z = fmaf(xv.x, wv0.z, acc[i].z); acc[i].z = fmaf(xv.y, wv1.z, acc[i].z);
                acc[i].z = fmaf(xv.z, wv2.z, acc[i].z); acc[i].z = fmaf(xv.w, wv3.z, acc[i].z);
                acc[i].w = fmaf(xv.x, wv0.w, acc[i].w); acc[i].w = fmaf(xv.y, wv1.w, acc[i].w);
                acc[i].w = fmaf(xv.z, wv2.w, acc[i].w); acc[i].w = fmaf(xv.w, wv3.w, acc[i].w);
            }
        }
        __syncthreads();
    }
    float4 bv = *(const float4*)(bias + ct * 4);
#pragma unroll
    for (int i = 0; i < 8; ++i) {
        float4 r;
        r.x = acc[i].x + bv.x; r.y = acc[i].y + bv.y;
        r.z = acc[i].z + bv.z; r.w = acc[i].w + bv.w;
        *(float4*)(out + (size_t)(nb + nt * 8 + i) * 128 + ct * 4) = r;
    }
}

// ---------------- GATv2 edge aggregation + head maxpool ----------------
// one wave per dst node; lane l owns dims (2l, 2l+1) of the H*D=128 layout; head = lane>>4
__global__ __launch_bounds__(256) void k_edge(const float* __restrict__ fs, const float* __restrict__ fd,
                                              const int* __restrict__ rowptr, const int* __restrict__ col,
                                              const float* __restrict__ attn, float* __restrict__ hout) {
    int w = threadIdx.x >> 6, lane = threadIdx.x & 63;
    int n = blockIdx.x * 4 + w;
    float2 av  = ((const float2*)attn)[lane];
    float2 fdv = *(const float2*)(fd + (size_t)n * 128 + lane * 2);
    int start = rowptr[n], end = rowptr[n + 1];
    float m = -INFINITY, z = 0.f, a0 = 0.f, a1 = 0.f;
    for (int cs = start; cs < end; cs += 64) {
        int cnt = min(64, end - cs);
        int mysrc = (lane < cnt) ? col[cs + lane] : 0;
        for (int j = 0; j < cnt; ++j) {
            int s = __shfl(mysrc, j);
            float2 fv = *(const float2*)(fs + (size_t)s * 128 + lane * 2);
            float e0 = fv.x + fdv.x; e0 = fmaxf(e0, NEG * e0);
            float e1 = fv.y + fdv.y; e1 = fmaxf(e1, NEG * e1);
            float sp = fmaf(e0, av.x, e1 * av.y);
            sp += __shfl_xor(sp, 1);
            sp += __shfl_xor(sp, 2);
            sp += __shfl_xor(sp, 4);
            sp += __shfl_xor(sp, 8);   // s for this head, broadcast to its 16 lanes
            float nm = fmaxf(m, sp);
            float so = __expf(m - nm);
            float p  = __expf(sp - nm);
            z  = fmaf(z, so, p);
            a0 = fmaf(a0, so, p * fv.x);
            a1 = fmaf(a1, so, p * fv.y);
            m = nm;
        }
    }
    float r = (z > 0.f) ? 1.f / z : 0.f;  // deg==0 -> output 0 (matches empty segment_sum)
    a0 *= r; a1 *= r;
    // maxpool over heads: lanes {l, l^16, l^32, l^48} hold same within-head dims
    a0 = fmaxf(a0, __shfl_xor(a0, 16)); a0 = fmaxf(a0, __shfl_xor(a0, 32));
    a1 = fmaxf(a1, __shfl_xor(a1, 16)); a1 = fmaxf(a1, __shfl_xor(a1, 32));
    if (lane < 16)
        *(float2*)(hout + (size_t)n * 32 + lane * 2) = make_float2(a0, a1);
}

// ---------------- global attention pooling ----------------
__global__ __launch_bounds__(256) void k_pool(const float* __restrict__ h2, const float* __restrict__ gW,
                                              const float* __restrict__ gb, float* __restrict__ out) {
    int b = blockIdx.x, tid = threadIdx.x;
    __shared__ float ga[NPG];
    __shared__ float red[256];
    __shared__ float gws[32];
    const float* hb = h2 + (size_t)b * NPG * 32;
    if (tid < 32) gws[tid] = gW[tid];
    __syncthreads();
    float gbv = gb[0];
    float lmax = -INFINITY;
    float gloc[4];
#pragma unroll
    for (int j = 0; j < 4; ++j) {
        int nl = tid + j * 256;
        const float* row = hb + nl * 32;
        float dot = 0.f;
#pragma unroll
        for (int c = 0; c < 32; c += 4) {
            float4 v = *(const float4*)(row + c);
            dot += v.x * gws[c] + v.y * gws[c + 1] + v.z * gws[c + 2] + v.w * gws[c + 3];
        }
        gloc[j] = dot + gbv;
        lmax = fmaxf(lmax, gloc[j]);
    }
    red[tid] = lmax; __syncthreads();
    for (int s2 = 128; s2 > 0; s2 >>= 1) { if (tid < s2) red[tid] = fmaxf(red[tid], red[tid + s2]); __syncthreads(); }
    float m = red[0];
    __syncthreads();
    float lsum = 0.f;
#pragma unroll
    for (int j = 0; j < 4; ++j) {
        int nl = tid + j * 256;
        float a = __expf(gloc[j] - m);
        ga[nl] = a;
        lsum += a;
    }
    red[tid] = lsum; __syncthreads();
    for (int s2 = 128; s2 > 0; s2 >>= 1) { if (tid < s2) red[tid] += red[tid + s2]; __syncthreads(); }
    float z = red[0];
    __syncthreads();
    int d = tid & 31, ng = tid >> 5;
    float acc = 0.f;
    for (int nl = ng; nl < NPG; nl += 8) acc += ga[nl] * hb[nl * 32 + d];
    red[tid] = acc; __syncthreads();
    if (tid < 32) {
        float s = red[tid];
#pragma unroll
        for (int g2 = 1; g2 < 8; ++g2) s += red[g2 * 32 + tid];
        out[b * 32 + tid] = s / z;
    }
}

extern "C" void kernel_launch(void* const* d_in, const int* in_sizes, int n_in,
                              void* d_out, int out_size, void* d_ws, size_t ws_size,
                              hipStream_t stream) {
    const float* x     = (const float*)d_in[0];
    const int*   src   = (const int*)d_in[1];
    const int*   dst   = (const int*)d_in[2];
    // d_in[3] = gid (unused: graphs are contiguous 1024-node blocks)
    const float* Ws1   = (const float*)d_in[4];
    const float* bs1   = (const float*)d_in[5];
    const float* Wd1   = (const float*)d_in[6];
    const float* bd1   = (const float*)d_in[7];
    const float* attn1 = (const float*)d_in[8];
    const float* Ws2   = (const float*)d_in[9];
    const float* bs2   = (const float*)d_in[10];
    const float* Wd2   = (const float*)d_in[11];
    const float* bd2   = (const float*)d_in[12];
    const float* attn2 = (const float*)d_in[13];
    const float* gW    = (const float*)d_in[14];
    const float* gb    = (const float*)d_in[15];
    float* out = (float*)d_out;

    // workspace layout (88.6 MB total)
    float* fs = (float*)d_ws;                        // N*128
    float* fd = fs + (size_t)N_NODES * 128;          // N*128
    float* h1 = fd + (size_t)N_NODES * 128;          // N*32
    float* h2 = h1 + (size_t)N_NODES * 32;           // N*32
    int* rowptr = (int*)(h2 + (size_t)N_NODES * 32); // N+1
    int* cursor = rowptr + (N_NODES + 4);            // N
    int* col    = cursor + N_NODES;                  // E

    // CSR build (reused by both layers)
    hipMemsetAsync(cursor, 0, N_NODES * sizeof(int), stream);
    k_deg<<<E_TOTAL / 256, 256, 0, stream>>>(dst, cursor);
    k_scan<<<B_GRAPHS, 256, 0, stream>>>(cursor, rowptr);
    k_scatter<<<E_TOTAL / 256, 256, 0, stream>>>(src, dst, cursor, col);

    // layer 1
    k_gemm<128><<<N_NODES / 64, 256, 0, stream>>>(x, Ws1, bs1, fs);
    k_gemm<128><<<N_NODES / 64, 256, 0, stream>>>(x, Wd1, bd1, fd);
    k_edge<<<N_NODES / 4, 256, 0, stream>>>(fs, fd, rowptr, col, attn1, h1);

    // layer 2 (reuses fs/fd buffers)
    k_gemm<32><<<N_NODES / 64, 256, 0, stream>>>(h1, Ws2, bs2, fs);
    k_gemm<32><<<N_NODES / 64, 256, 0, stream>>>(h1, Wd2, bd2, fd);
    k_edge<<<N_NODES / 4, 256, 0, stream>>>(fs, fd, rowptr, col, attn2, h2);

    // global attention pooling
    k_pool<<<B_GRAPHS, 256, 0, stream>>>(h2, gW, gb, out);
}

// Round 2
// 298.244 us; speedup vs baseline: 1.2791x; 1.2791x over previous
//
#include <hip/hip_runtime.h>
#include <math.h>

#define N_NODES 65536
#define B_GRAPHS 64
#define NPG 1024
#define EPG 16384
#define E_TOTAL (B_GRAPHS * EPG)
#define NEG 0.2f

// ---------------- DPP 16-lane reduce (head groups = DPP rows) ----------------
template <int CTRL>
__device__ __forceinline__ float dpp_add(float v) {
    int x = __builtin_amdgcn_update_dpp(0, __float_as_int(v), CTRL, 0xf, 0xf, true);
    return v + __int_as_float(x);
}
__device__ __forceinline__ float hsum16(float v) {
    v = dpp_add<0xB1>(v);   // quad_perm [1,0,3,2]  (xor 1)
    v = dpp_add<0x4E>(v);   // quad_perm [2,3,0,1]  (xor 2)
    v = dpp_add<0x124>(v);  // row_ror:4
    v = dpp_add<0x128>(v);  // row_ror:8
    return v;               // all 16 lanes of the row hold the sum
}

// ---------------- CSR build ----------------
__global__ void k_deg(const int* __restrict__ dst, int* __restrict__ cnt) {
    int i = blockIdx.x * 256 + threadIdx.x;
    if (i < E_TOTAL) atomicAdd(&cnt[dst[i]], 1);
}

// one block per graph: exclusive scan of 1024 degrees, base = b*EPG
__global__ __launch_bounds__(256) void k_scan(int* __restrict__ cursor, int* __restrict__ rowptr) {
    int b = blockIdx.x, tid = threadIdx.x;
    __shared__ int ps[256];
    int idx = b * NPG + tid * 4;
    int v0 = cursor[idx], v1 = cursor[idx + 1], v2 = cursor[idx + 2], v3 = cursor[idx + 3];
    ps[tid] = v0 + v1 + v2 + v3;
    __syncthreads();
    for (int off = 1; off < 256; off <<= 1) {
        int u = (tid >= off) ? ps[tid - off] : 0;
        __syncthreads();
        ps[tid] += u;
        __syncthreads();
    }
    int ex = (tid ? ps[tid - 1] : 0) + b * EPG;
    int r0 = ex, r1 = r0 + v0, r2 = r1 + v1, r3 = r2 + v2;
    rowptr[idx] = r0; rowptr[idx + 1] = r1; rowptr[idx + 2] = r2; rowptr[idx + 3] = r3;
    cursor[idx] = r0; cursor[idx + 1] = r1; cursor[idx + 2] = r2; cursor[idx + 3] = r3;
    if (b == 0 && tid == 0) rowptr[N_NODES] = E_TOTAL;
}

__global__ void k_scatter(const int* __restrict__ src, const int* __restrict__ dst,
                          int* __restrict__ cursor, int* __restrict__ col) {
    int i = blockIdx.x * 256 + threadIdx.x;
    if (i < E_TOTAL) {
        int d = dst[i];
        int p = atomicAdd(&cursor[d], 1);
        col[p] = src[i];
    }
}

// ---------------- dual node GEMM: fs = X@Ws+bs, fd = X@Wd+bd (128 cols each) ----------------
template <int K>
__global__ __launch_bounds__(256) void k_gemm_dual(const float* __restrict__ X,
                                                   const float* __restrict__ Ws, const float* __restrict__ bs,
                                                   const float* __restrict__ Wd, const float* __restrict__ bd,
                                                   float* __restrict__ outs, float* __restrict__ outd) {
    __shared__ float xs[64 * 32];     // 64 nodes x 32 k
    __shared__ float wss[32 * 128];   // 32 k x 128 c
    __shared__ float wds[32 * 128];
    int tid = threadIdx.x;
    int ct = tid & 31;   // 32 col-tiles of 4
    int nt = tid >> 5;   // 8 node-tiles of 8
    int nb = blockIdx.x * 64;
    float4 accs[8], accd[8];
#pragma unroll
    for (int i = 0; i < 8; ++i) { accs[i] = make_float4(0.f, 0.f, 0.f, 0.f); accd[i] = make_float4(0.f, 0.f, 0.f, 0.f); }

    for (int k0 = 0; k0 < K; k0 += 32) {
        for (int j = tid; j < 512; j += 256) {
            int r = j >> 3, c4 = j & 7;
            *(float4*)(xs + r * 32 + c4 * 4) = *(const float4*)(X + (size_t)(nb + r) * K + k0 + c4 * 4);
        }
        for (int j = tid; j < 1024; j += 256) {
            *(float4*)(wss + j * 4) = *(const float4*)(Ws + (size_t)k0 * 128 + j * 4);
            *(float4*)(wds + j * 4) = *(const float4*)(Wd + (size_t)k0 * 128 + j * 4);
        }
        __syncthreads();
#pragma unroll
        for (int k4 = 0; k4 < 8; ++k4) {
            float4 s0 = *(const float4*)(wss + (k4 * 4 + 0) * 128 + ct * 4);
            float4 s1 = *(const float4*)(wss + (k4 * 4 + 1) * 128 + ct * 4);
            float4 s2 = *(const float4*)(wss + (k4 * 4 + 2) * 128 + ct * 4);
            float4 s3 = *(const float4*)(wss + (k4 * 4 + 3) * 128 + ct * 4);
            float4 d0 = *(const float4*)(wds + (k4 * 4 + 0) * 128 + ct * 4);
            float4 d1 = *(const float4*)(wds + (k4 * 4 + 1) * 128 + ct * 4);
            float4 d2 = *(const float4*)(wds + (k4 * 4 + 2) * 128 + ct * 4);
            float4 d3 = *(const float4*)(wds + (k4 * 4 + 3) * 128 + ct * 4);
#pragma unroll
            for (int i = 0; i < 8; ++i) {
                float4 xv = *(const float4*)(xs + (nt * 8 + i) * 32 + k4 * 4);
                accs[i].x = fmaf(xv.x, s0.x, accs[i].x); accs[i].x = fmaf(xv.y, s1.x, accs[i].x);
                accs[i].x = fmaf(xv.z, s2.x, accs[i].x); accs[i].x = fmaf(xv.w, s3.x, accs[i].x);
                accs[i].y = fmaf(xv.x, s0.y, accs[i].y); accs[i].y = fmaf(xv.y, s1.y, accs[i].y);
                accs[i].y = fmaf(xv.z, s2.y, accs[i].y); accs[i].y = fmaf(xv.w, s3.y, accs[i].y);
                accs[i].z = fmaf(xv.x, s0.z, accs[i].z); accs[i].z = fmaf(xv.y, s1.z, accs[i].z);
                accs[i].z = fmaf(xv.z, s2.z, accs[i].z); accs[i].z = fmaf(xv.w, s3.z, accs[i].z);
                accs[i].w = fmaf(xv.x, s0.w, accs[i].w); accs[i].w = fmaf(xv.y, s1.w, accs[i].w);
                accs[i].w = fmaf(xv.z, s2.w, accs[i].w); accs[i].w = fmaf(xv.w, s3.w, accs[i].w);
                accd[i].x = fmaf(xv.x, d0.x, accd[i].x); accd[i].x = fmaf(xv.y, d1.x, accd[i].x);
                accd[i].x = fmaf(xv.z, d2.x, accd[i].x); accd[i].x = fmaf(xv.w, d3.x, accd[i].x);
                accd[i].y = fmaf(xv.x, d0.y, accd[i].y); accd[i].y = fmaf(xv.y, d1.y, accd[i].y);
                accd[i].y = fmaf(xv.z, d2.y, accd[i].y); accd[i].y = fmaf(xv.w, d3.y, accd[i].y);
                accd[i].z = fmaf(xv.x, d0.z, accd[i].z); accd[i].z = fmaf(xv.y, d1.z, accd[i].z);
                accd[i].z = fmaf(xv.z, d2.z, accd[i].z); accd[i].z = fmaf(xv.w, d3.z, accd[i].z);
                accd[i].w = fmaf(xv.x, d0.w, accd[i].w); accd[i].w = fmaf(xv.y, d1.w, accd[i].w);
                accd[i].w = fmaf(xv.z, d2.w, accd[i].w); accd[i].w = fmaf(xv.w, d3.w, accd[i].w);
            }
        }
        __syncthreads();
    }
    float4 bsv = *(const float4*)(bs + ct * 4);
    float4 bdv = *(const float4*)(bd + ct * 4);
#pragma unroll
    for (int i = 0; i < 8; ++i) {
        float4 r;
        r.x = accs[i].x + bsv.x; r.y = accs[i].y + bsv.y; r.z = accs[i].z + bsv.z; r.w = accs[i].w + bsv.w;
        *(float4*)(outs + (size_t)(nb + nt * 8 + i) * 128 + ct * 4) = r;
        r.x = accd[i].x + bdv.x; r.y = accd[i].y + bdv.y; r.z = accd[i].z + bdv.z; r.w = accd[i].w + bdv.w;
        *(float4*)(outd + (size_t)(nb + nt * 8 + i) * 128 + ct * 4) = r;
    }
}

// ---------------- GATv2 edge aggregation + head maxpool ----------------
// one wave per dst node; lane l owns dims (2l,2l+1); head = lane>>4 = DPP row.
// softmax computed WITHOUT max subtraction (shift-invariant; logits |s|<~6 here,
// clamped at +-80 in log2 domain as insurance) -> no loop-carried max chain.
__global__ __launch_bounds__(256) void k_edge(const float* __restrict__ fs, const float* __restrict__ fd,
                                              const int* __restrict__ rowptr, const int* __restrict__ col,
                                              const float* __restrict__ attn, float* __restrict__ hout) {
    int w = threadIdx.x >> 6, lane = threadIdx.x & 63;
    int n = blockIdx.x * 4 + w;
    float2 av = ((const float2*)attn)[lane];
    av.x *= 1.44269504089f;   // fold log2(e) into attn -> exp2 needs no per-edge mul
    av.y *= 1.44269504089f;
    float2 fdv = *(const float2*)(fd + ((size_t)n << 7) + (lane << 1));
    int start = __builtin_amdgcn_readfirstlane(rowptr[n]);
    int end   = __builtin_amdgcn_readfirstlane(rowptr[n + 1]);
    float z = 0.f, a0 = 0.f, a1 = 0.f;
    float z2 = 0.f, b0 = 0.f, b1 = 0.f;   // second accumulator set breaks fma chains
    for (int j = start; j < end; j += 8) {
        int rem = end - j;   // >= 1
        int sv[8];
        float2 fv[8];
        float p[8];
#pragma unroll
        for (int u = 0; u < 8; ++u) {
            int jj = j + ((u < rem) ? u : rem - 1);   // uniform -> scalar loads
            sv[u] = col[jj];
        }
#pragma unroll
        for (int u = 0; u < 8; ++u)
            fv[u] = *(const float2*)(fs + ((size_t)sv[u] << 7) + (lane << 1));
#pragma unroll
        for (int u = 0; u < 8; ++u) {
            float e0 = fv[u].x + fdv.x; e0 = fmaxf(e0, NEG * e0);
            float e1 = fv[u].y + fdv.y; e1 = fmaxf(e1, NEG * e1);
            float sp = fmaf(e1, av.y, e0 * av.x);
            sp = hsum16(sp);                       // per-head logit (log2 domain)
            sp = fminf(fmaxf(sp, -80.f), 80.f);
            float pe = exp2f(sp);
            p[u] = (u < rem) ? pe : 0.f;
        }
#pragma unroll
        for (int u = 0; u < 8; u += 2) {
            z  += p[u];     a0 = fmaf(p[u],     fv[u].x,     a0); a1 = fmaf(p[u],     fv[u].y,     a1);
            z2 += p[u + 1]; b0 = fmaf(p[u + 1], fv[u + 1].x, b0); b1 = fmaf(p[u + 1], fv[u + 1].y, b1);
        }
    }
    z += z2; a0 += b0; a1 += b1;
    float r = (z > 0.f) ? 1.f / z : 0.f;   // deg==0 -> output 0 (matches empty segment_sum)
    a0 *= r; a1 *= r;
    // maxpool over heads: lanes {l, l^16, l^32, l^48} hold the same within-head dims
    a0 = fmaxf(a0, __shfl_xor(a0, 16)); a0 = fmaxf(a0, __shfl_xor(a0, 32));
    a1 = fmaxf(a1, __shfl_xor(a1, 16)); a1 = fmaxf(a1, __shfl_xor(a1, 32));
    if (lane < 16)
        *(float2*)(hout + ((size_t)n << 5) + (lane << 1)) = make_float2(a0, a1);
}

// ---------------- global attention pooling ----------------
__global__ __launch_bounds__(256) void k_pool(const float* __restrict__ h2, const float* __restrict__ gW,
                                              const float* __restrict__ gb, float* __restrict__ out) {
    int b = blockIdx.x, tid = threadIdx.x;
    __shared__ float ga[NPG];
    __shared__ float red[256];
    __shared__ float gws[32];
    const float* hb = h2 + (size_t)b * NPG * 32;
    if (tid < 32) gws[tid] = gW[tid];
    __syncthreads();
    float gbv = gb[0];
    float lmax = -INFINITY;
    float gloc[4];
#pragma unroll
    for (int j = 0; j < 4; ++j) {
        int nl = tid + j * 256;
        const float* row = hb + nl * 32;
        float dot = 0.f;
#pragma unroll
        for (int c = 0; c < 32; c += 4) {
            float4 v = *(const float4*)(row + c);
            dot += v.x * gws[c] + v.y * gws[c + 1] + v.z * gws[c + 2] + v.w * gws[c + 3];
        }
        gloc[j] = dot + gbv;
        lmax = fmaxf(lmax, gloc[j]);
    }
    red[tid] = lmax; __syncthreads();
    for (int s2 = 128; s2 > 0; s2 >>= 1) { if (tid < s2) red[tid] = fmaxf(red[tid], red[tid + s2]); __syncthreads(); }
    float m = red[0];
    __syncthreads();
    float lsum = 0.f;
#pragma unroll
    for (int j = 0; j < 4; ++j) {
        int nl = tid + j * 256;
        float a = __expf(gloc[j] - m);
        ga[nl] = a;
        lsum += a;
    }
    red[tid] = lsum; __syncthreads();
    for (int s2 = 128; s2 > 0; s2 >>= 1) { if (tid < s2) red[tid] += red[tid + s2]; __syncthreads(); }
    float z = red[0];
    __syncthreads();
    int d = tid & 31, ng = tid >> 5;
    float acc = 0.f;
    for (int nl = ng; nl < NPG; nl += 8) acc += ga[nl] * hb[nl * 32 + d];
    red[tid] = acc; __syncthreads();
    if (tid < 32) {
        float s = red[tid];
#pragma unroll
        for (int g2 = 1; g2 < 8; ++g2) s += red[g2 * 32 + tid];
        out[b * 32 + tid] = s / z;
    }
}

extern "C" void kernel_launch(void* const* d_in, const int* in_sizes, int n_in,
                              void* d_out, int out_size, void* d_ws, size_t ws_size,
                              hipStream_t stream) {
    const float* x     = (const float*)d_in[0];
    const int*   src   = (const int*)d_in[1];
    const int*   dst   = (const int*)d_in[2];
    // d_in[3] = gid (unused: graphs are contiguous 1024-node blocks)
    const float* Ws1   = (const float*)d_in[4];
    const float* bs1   = (const float*)d_in[5];
    const float* Wd1   = (const float*)d_in[6];
    const float* bd1   = (const float*)d_in[7];
    const float* attn1 = (const float*)d_in[8];
    const float* Ws2   = (const float*)d_in[9];
    const float* bs2   = (const float*)d_in[10];
    const float* Wd2   = (const float*)d_in[11];
    const float* bd2   = (const float*)d_in[12];
    const float* attn2 = (const float*)d_in[13];
    const float* gW    = (const float*)d_in[14];
    const float* gb    = (const float*)d_in[15];
    float* out = (float*)d_out;

    // workspace layout (~89 MB)
    float* fs = (float*)d_ws;                        // N*128
    float* fd = fs + (size_t)N_NODES * 128;          // N*128
    float* h1 = fd + (size_t)N_NODES * 128;          // N*32
    float* h2 = h1 + (size_t)N_NODES * 32;           // N*32
    int* rowptr = (int*)(h2 + (size_t)N_NODES * 32); // N+1
    int* cursor = rowptr + (N_NODES + 4);            // N
    int* col    = cursor + N_NODES;                  // E

    // CSR build (reused by both layers)
    hipMemsetAsync(cursor, 0, N_NODES * sizeof(int), stream);
    k_deg<<<E_TOTAL / 256, 256, 0, stream>>>(dst, cursor);
    k_scan<<<B_GRAPHS, 256, 0, stream>>>(cursor, rowptr);
    k_scatter<<<E_TOTAL / 256, 256, 0, stream>>>(src, dst, cursor, col);

    // layer 1
    k_gemm_dual<128><<<N_NODES / 64, 256, 0, stream>>>(x, Ws1, bs1, Wd1, bd1, fs, fd);
    k_edge<<<N_NODES / 4, 256, 0, stream>>>(fs, fd, rowptr, col, attn1, h1);

    // layer 2 (reuses fs/fd buffers)
    k_gemm_dual<32><<<N_NODES / 64, 256, 0, stream>>>(h1, Ws2, bs2, Wd2, bd2, fs, fd);
    k_edge<<<N_NODES / 4, 256, 0, stream>>>(fs, fd, rowptr, col, attn2, h2);

    // global attention pooling
    k_pool<<<B_GRAPHS, 256, 0, stream>>>(h2, gW, gb, out);
}